// Round 5
// baseline (328.561 us; speedup 1.0000x reference)
//
#include <hip/hip_runtime.h>
#include <hip/hip_bf16.h>
#include <hip/hip_fp8.h>
#include <stdint.h>

#define NN 50000
#define NE 800000
#define F 128
#define NCLS 16
#define NB 196          // ceil(NN/256) buckets
#define BCAP 5120       // per-bucket capacity: mean 4096 + 16 sigma
#define PA_EPT 16       // edges per thread in pass_a

typedef __attribute__((ext_vector_type(8))) short short8;
typedef __attribute__((ext_vector_type(4))) float f32x4;
typedef __attribute__((ext_vector_type(2))) float f32x2;
typedef __attribute__((ext_vector_type(4))) unsigned int uint4v;

// ---- ws byte offsets ----
#define OB_COLSUM    0u          // float[128]
#define OB_BCUR      512u        // int[196]
#define OB_BBASE     1536u       // int[196]
#define OB_ROWSTART  4096u       // int[50001]
#define OB_INVDEG    204800u     // float[50000]
#define OB_PAIRS     409600u     // u32[196*5120]
#define OB_SRCS16    4423680u    // u16[800000]
#define OB_WT        6023680u    // bf16 6*16384 (layout L)
#define OB_XB        6220800u    // bf16 [NN][128] layout L (doubles as HB2)
#define OB_HB1       19020800u
#define OB_X8        31820800u   // fp8 [NN][128] row-major
#define OB_F8A       38220800u
#define OB_F8B       44620800u   // ends 51020800

// ---- swizzled bf16 feature layout L ----
// element (row,k) at byte: row*256 + 16*(chunk(k) ^ (row&15)) + inchunk(k)
// chunk(k) = (k>>5)*4 | ((k>>2)&3); inchunk = ((k>>4)&1)*8 + (k&3)*2
__device__ __forceinline__ uint32_t swz_off(uint32_t row, uint32_t k) {
    uint32_t c = ((k >> 5) << 2) | ((k >> 2) & 3u);
    uint32_t b = (((k >> 4) & 1u) << 3) | ((k & 3u) << 1);
    return (row << 8) + (((c ^ (row & 15u)) << 4) | b);
}

__device__ __forceinline__ uint32_t pack_bf2(float a, float b) {
    __hip_bfloat16 l = __float2bfloat16(a), h = __float2bfloat16(b);
    return ((uint32_t)(*(uint16_t*)&h) << 16) | (uint32_t)(*(uint16_t*)&l);
}

__device__ __forceinline__ uint8_t f32_to_fp8(float v) {
#if __has_builtin(__builtin_amdgcn_cvt_pk_fp8_f32)
    return (uint8_t)(__builtin_amdgcn_cvt_pk_fp8_f32(v, 0.f, 0, false) & 0xff);
#else
    __hip_fp8_e4m3 t(v);
    return t.__x;
#endif
}

__device__ __forceinline__ uint32_t f32x4_to_fp8x4(float a, float b, float c, float d) {
#if __has_builtin(__builtin_amdgcn_cvt_pk_fp8_f32)
    int r = __builtin_amdgcn_cvt_pk_fp8_f32(a, b, 0, false);
    r = __builtin_amdgcn_cvt_pk_fp8_f32(c, d, r, true);
    return (uint32_t)r;
#else
    __hip_fp8_e4m3 ta(a), tb(b), tc(c), td(d);
    return (uint32_t)ta.__x | ((uint32_t)tb.__x << 8) | ((uint32_t)tc.__x << 16) | ((uint32_t)td.__x << 24);
#endif
}

__device__ __forceinline__ void fp8x4_to_f32(uint32_t d, float& f0, float& f1, float& f2, float& f3) {
#if __has_builtin(__builtin_amdgcn_cvt_pk_f32_fp8)
    f32x2 lo = __builtin_amdgcn_cvt_pk_f32_fp8((int)d, false);
    f32x2 hi = __builtin_amdgcn_cvt_pk_f32_fp8((int)d, true);
    f0 = lo.x; f1 = lo.y; f2 = hi.x; f3 = hi.y;
#else
    __hip_fp8_e4m3 t0, t1, t2, t3;
    t0.__x = (uint8_t)(d & 0xff); t1.__x = (uint8_t)((d >> 8) & 0xff);
    t2.__x = (uint8_t)((d >> 16) & 0xff); t3.__x = (uint8_t)((d >> 24) & 0xff);
    f0 = (float)t0; f1 = (float)t1; f2 = (float)t2; f3 = (float)t3;
#endif
}

// ====== init: zero colsum, set bucket cursors to bucket bases ======
__global__ void init_kernel(float* __restrict__ colsum, int* __restrict__ bcur) {
    int t = threadIdx.x;
    if (t < 128) colsum[t] = 0.f;
    if (t < NB) bcur[t] = t * BCAP;
}

// ====== convert x to bf16 layout L + fp8 row-major copy ======
__global__ __launch_bounds__(256) void convert_x2(const float* __restrict__ x,
                                                  uint8_t* __restrict__ xb,
                                                  uint8_t* __restrict__ x8) {
    int t = blockIdx.x * 256 + threadIdx.x;          // NN*32 quad-slots
    uint32_t row = (uint32_t)t >> 5;
    uint32_t q = (uint32_t)t & 31u;                  // 4-k group
    float4 v = *(const float4*)(x + row * F + q * 4);
    uint32_t c = ((q >> 3) << 2) | (q & 3u);
    uint32_t hi = (q >> 2) & 1u;
    uint2 pk;
    pk.x = pack_bf2(v.x, v.y);
    pk.y = pack_bf2(v.z, v.w);
    *(uint2*)(xb + (row << 8) + (((c ^ (row & 15u)) << 4) | (hi << 3))) = pk;
    *(uint32_t*)(x8 + row * 128u + q * 4u) = f32x4_to_fp8x4(v.x, v.y, v.z, v.w);
}

// transpose + convert weights: Wt[n][k] = W[k][n], layout L on (n,k)
__global__ __launch_bounds__(256) void prep_w(const float* __restrict__ w0, const float* __restrict__ w1,
                                              const float* __restrict__ w2, const float* __restrict__ w3,
                                              const float* __restrict__ w4, const float* __restrict__ w5,
                                              uint8_t* __restrict__ wt) {
    int m = blockIdx.y;
    const float* w = m == 0 ? w0 : m == 1 ? w1 : m == 2 ? w2 : m == 3 ? w3 : m == 4 ? w4 : w5;
    int t = blockIdx.x * 256 + threadIdx.x;          // 8192 pair-slots
    int n = t >> 6;
    int k0 = (t & 63) << 1;
    uint32_t pk = pack_bf2(w[k0 * F + n], w[(k0 + 1) * F + n]);
    *(uint32_t*)(wt + (uint32_t)m * 32768u + swz_off((uint32_t)n, (uint32_t)k0)) = pk;
}

// ====== pass A: LDS-aggregated scatter into fixed-capacity bucket streams ======
__global__ __launch_bounds__(256) void pass_a(const int* __restrict__ src,
                                              const int* __restrict__ dst,
                                              int* __restrict__ bcur,
                                              uint32_t* __restrict__ pairs) {
    __shared__ int cnt[NB];
    __shared__ int base_s[NB];
    int t = threadIdx.x;
    for (int i = t; i < NB; i += 256) cnt[i] = 0;
    __syncthreads();

    uint32_t pk[PA_EPT];
    int bk[PA_EPT];
    int e0 = blockIdx.x * (256 * PA_EPT) + t;
#pragma unroll
    for (int j = 0; j < PA_EPT; ++j) {
        int e = e0 + j * 256;
        if (e < NE) {
            int sv = src[e], dv = dst[e];
            bk[j] = dv >> 8;
            pk[j] = (uint32_t)sv | (((uint32_t)dv & 255u) << 16);
            atomicAdd(&cnt[bk[j]], 1);
        } else bk[j] = -1;
    }
    __syncthreads();
    for (int i = t; i < NB; i += 256) {
        if (cnt[i] > 0) base_s[i] = atomicAdd(&bcur[i], cnt[i]);
        cnt[i] = 0;   // reuse as local cursor
    }
    __syncthreads();
#pragma unroll
    for (int j = 0; j < PA_EPT; ++j) {
        if (bk[j] >= 0) {
            int pos = base_s[bk[j]] + atomicAdd(&cnt[bk[j]], 1);
            pairs[pos] = pk[j];
        }
    }
}

// ====== bucket base scan (196 fills -> contiguous CSR bases) ======
__global__ __launch_bounds__(256) void bucket_scan(const int* __restrict__ bcur,
                                                   int* __restrict__ bbase,
                                                   int* __restrict__ row_start) {
    __shared__ int s[256];
    int t = threadIdx.x;
    int fill = (t < NB) ? (bcur[t] - t * BCAP) : 0;
    s[t] = fill;
    __syncthreads();
    for (int off = 1; off < 256; off <<= 1) {
        int u = (t >= off) ? s[t - off] : 0;
        __syncthreads();
        s[t] += u;
        __syncthreads();
    }
    if (t < NB) bbase[t] = s[t] - fill;   // exclusive
    if (t == 0) row_start[NN] = NE;
}

// ====== pass B: per-bucket count/scan, emit row_start+inv_deg+srcs16 ======
__global__ __launch_bounds__(256) void pass_b(const uint32_t* __restrict__ pairs,
                                              const int* __restrict__ bcur,
                                              const int* __restrict__ bbase,
                                              int* __restrict__ row_start,
                                              float* __restrict__ inv_deg,
                                              unsigned short* __restrict__ srcs) {
    __shared__ int cnt[256];
    __shared__ int s[256];
    __shared__ int cur[256];
    int b = blockIdx.x, t = threadIdx.x;
    int in0 = b * BCAP;
    int fill = bcur[b] - in0;
    int out0 = bbase[b];
    cnt[t] = 0;
    __syncthreads();
    for (int i = t; i < fill; i += 256)
        atomicAdd(&cnt[pairs[in0 + i] >> 16], 1);
    __syncthreads();
    int v = cnt[t];
    s[t] = v;
    __syncthreads();
    for (int off = 1; off < 256; off <<= 1) {
        int u = (t >= off) ? s[t - off] : 0;
        __syncthreads();
        s[t] += u;
        __syncthreads();
    }
    int excl = s[t] - v;
    cur[t] = out0 + excl;
    int row = (b << 8) + t;
    if (row < NN) {
        row_start[row] = out0 + excl;
        inv_deg[row] = 1.0f / (float)(v > 1 ? v : 1);
    }
    __syncthreads();
    for (int i = t; i < fill; i += 256) {
        uint32_t p = pairs[in0 + i];
        int pos = atomicAdd(&cur[p >> 16], 1);
        srcs[pos] = (unsigned short)(p & 0xffffu);
    }
}

// ====== fused layer: aggregate(fp8 gather)+GEMM(MFMA)+relu+stores ======
__global__ __launch_bounds__(256) void sage_layer(
        const uint8_t* __restrict__ hb16,      // self input, bf16 layout L
        const uint8_t* __restrict__ hf8,       // agg input, fp8 row-major 128B rows
        const int* __restrict__ row_start, const unsigned short* __restrict__ srcs,
        const float* __restrict__ inv_deg,
        const uint8_t* __restrict__ wt_self, const uint8_t* __restrict__ wt_neigh,
        const float* __restrict__ bias,
        uint8_t* __restrict__ hout_b16, uint8_t* __restrict__ hout_f8,
        float* colsum) {
    __shared__ uint4v Ws4[2048];   // 32 KB: W (layout L, 128 n-rows)
    __shared__ uint4v As4[1024];   // 16 KB: A tile (layout L, 64 rows)
    __shared__ float cs[128];
    const int tid = threadIdx.x;
    const int lane = tid & 63, wave = tid >> 6;
    const int rl = lane & 15, g = lane >> 4;
    const int row0 = blockIdx.x * 64;
    const char* AsB = (const char*)As4;
    const char* WsB = (const char*)Ws4;

    // ---- phase A: stage Wn + aggregate fp8 rows into As4 ----
    {
        const uint4v* gw = (const uint4v*)wt_neigh;
#pragma unroll
        for (int i = 0; i < 8; ++i) Ws4[tid + i * 256] = gw[tid + i * 256];
    }
    {
        int slot = lane >> 5;                 // 2 nodes in parallel per wave
        uint32_t sub = (uint32_t)(lane & 31); // feature dword: k = sub*4..+3
        uint32_t c = ((sub >> 3) << 2) | (sub & 3u);
        uint32_t hi8 = ((sub >> 2) & 1u) << 3;
#pragma unroll 1
        for (int r = 0; r < 8; ++r) {
            int lr = wave * 16 + r * 2 + slot;
            int node = row0 + lr;
            bool valid = node < NN;
            int e0 = valid ? row_start[node] : 0;
            int e1 = valid ? row_start[node + 1] : 0;
            float a0 = 0.f, a1 = 0.f, a2 = 0.f, a3 = 0.f;
            int e = e0;
            for (; e + 7 < e1; e += 8) {
                uint32_t d[8];
#pragma unroll
                for (int j = 0; j < 8; ++j) {
                    uint32_t s = srcs[e + j];
                    d[j] = *(const uint32_t*)(hf8 + s * 128u + sub * 4u);
                }
#pragma unroll
                for (int j = 0; j < 8; ++j) {
                    float f0, f1, f2, f3;
                    fp8x4_to_f32(d[j], f0, f1, f2, f3);
                    a0 += f0; a1 += f1; a2 += f2; a3 += f3;
                }
            }
            for (; e < e1; ++e) {
                uint32_t s = srcs[e];
                uint32_t dv = *(const uint32_t*)(hf8 + s * 128u + sub * 4u);
                float f0, f1, f2, f3;
                fp8x4_to_f32(dv, f0, f1, f2, f3);
                a0 += f0; a1 += f1; a2 += f2; a3 += f3;
            }
            float idg = valid ? inv_deg[node] : 0.f;
            uint2 pk;
            pk.x = pack_bf2(a0 * idg, a1 * idg);
            pk.y = pack_bf2(a2 * idg, a3 * idg);
            *(uint2*)((char*)As4 + ((uint32_t)lr << 8) +
                      (((c ^ ((uint32_t)lr & 15u)) << 4) | hi8)) = pk;
        }
    }
    __syncthreads();

    f32x4 acc[8];
    f32x4 z = {0.f, 0.f, 0.f, 0.f};
#pragma unroll
    for (int nt = 0; nt < 8; ++nt) acc[nt] = z;

    // ---- MFMA pass: neigh ----
#pragma unroll
    for (int ks = 0; ks < 4; ++ks) {
        int chunk = ((ks << 2) | g) ^ rl;
        short8 a = *(const short8*)(AsB + ((wave * 16 + rl) << 8) + (chunk << 4));
#pragma unroll
        for (int nt = 0; nt < 8; ++nt) {
            short8 bb = *(const short8*)(WsB + ((nt * 16 + rl) << 8) + (chunk << 4));
            acc[nt] = __builtin_amdgcn_mfma_f32_16x16x32_bf16(a, bb, acc[nt], 0, 0, 0);
        }
    }
    __syncthreads();

    // ---- restage: self tile + Ws ----
    {
        const uint4v* ga = (const uint4v*)(hb16 + (size_t)row0 * 256);
#pragma unroll
        for (int i = 0; i < 4; ++i) As4[tid + i * 256] = ga[tid + i * 256];
        const uint4v* gw = (const uint4v*)wt_self;
#pragma unroll
        for (int i = 0; i < 8; ++i) Ws4[tid + i * 256] = gw[tid + i * 256];
    }
    __syncthreads();

    // ---- MFMA pass: self ----
#pragma unroll
    for (int ks = 0; ks < 4; ++ks) {
        int chunk = ((ks << 2) | g) ^ rl;
        short8 a = *(const short8*)(AsB + ((wave * 16 + rl) << 8) + (chunk << 4));
#pragma unroll
        for (int nt = 0; nt < 8; ++nt) {
            short8 bb = *(const short8*)(WsB + ((nt * 16 + rl) << 8) + (chunk << 4));
            acc[nt] = __builtin_amdgcn_mfma_f32_16x16x32_bf16(a, bb, acc[nt], 0, 0, 0);
        }
    }

    // ---- epilogue: bias + relu, bf16 L store + fp8 store (+ colsum) ----
    bool doCol = (colsum != nullptr);
    if (doCol) {
        if (tid < 128) cs[tid] = 0.f;
        __syncthreads();
    }
#pragma unroll
    for (int nt = 0; nt < 8; ++nt) {
        int col = nt * 16 + rl;
        float bv = bias[col];
        float rsum = 0.f;
#pragma unroll
        for (int i = 0; i < 4; ++i) {
            int row = row0 + wave * 16 + g * 4 + i;
            if (row < NN) {
                float v = fmaxf(acc[nt][i] + bv, 0.f);
                rsum += v;
                *(__hip_bfloat16*)(hout_b16 + swz_off((uint32_t)row, (uint32_t)col)) =
                    __float2bfloat16(v);
                hout_f8[(uint32_t)row * 128u + (uint32_t)col] = f32_to_fp8(v);
            }
        }
        if (doCol) atomicAdd(&cs[col], rsum);
    }
    if (doCol) {
        __syncthreads();
        if (tid < 128) atomicAdd(&colsum[tid], cs[tid]);
    }
}

__global__ __launch_bounds__(128) void head_kernel(const float* __restrict__ colsum,
                                                   const float* __restrict__ w_head,
                                                   const float* __restrict__ b_head,
                                                   float* __restrict__ out) {
    __shared__ float pls[F];
    int t = threadIdx.x;
    float p = colsum[t] * (1.0f / (float)NN);
    pls[t] = p;
    out[NCLS + t] = p;
    __syncthreads();
    if (t < NCLS) {
        float sc = b_head[t];
        for (int f = 0; f < F; ++f) sc += pls[f] * w_head[f * NCLS + t];
        out[t] = sc;
    }
}

extern "C" void kernel_launch(void* const* d_in, const int* in_sizes, int n_in,
                              void* d_out, int out_size, void* d_ws, size_t ws_size,
                              hipStream_t stream) {
    const float* x       = (const float*)d_in[0];
    const int*   src     = (const int*)d_in[1];
    const int*   dst     = (const int*)d_in[2];
    const float* w_self0 = (const float*)d_in[3];
    const float* w_neigh0= (const float*)d_in[4];
    const float* b0      = (const float*)d_in[5];
    const float* w_self1 = (const float*)d_in[6];
    const float* w_neigh1= (const float*)d_in[7];
    const float* b1      = (const float*)d_in[8];
    const float* w_self2 = (const float*)d_in[9];
    const float* w_neigh2= (const float*)d_in[10];
    const float* b2      = (const float*)d_in[11];
    const float* w_head  = (const float*)d_in[12];
    const float* b_head  = (const float*)d_in[13];
    float* out = (float*)d_out;

    uint8_t* ws = (uint8_t*)d_ws;
    float* colsum   = (float*)(ws + OB_COLSUM);
    int*   bcur     = (int*)(ws + OB_BCUR);
    int*   bbase    = (int*)(ws + OB_BBASE);
    int*   row_start= (int*)(ws + OB_ROWSTART);
    float* inv_deg  = (float*)(ws + OB_INVDEG);
    uint32_t* pairs = (uint32_t*)(ws + OB_PAIRS);
    unsigned short* srcs16 = (unsigned short*)(ws + OB_SRCS16);
    uint8_t* wt     = ws + OB_WT;
    uint8_t* xb     = ws + OB_XB;     // bf16 L; doubles as hb2
    uint8_t* hb1    = ws + OB_HB1;
    uint8_t* x8     = ws + OB_X8;
    uint8_t* f8a    = ws + OB_F8A;
    uint8_t* f8b    = ws + OB_F8B;

    init_kernel<<<1, 256, 0, stream>>>(colsum, bcur);
    convert_x2<<<6250, 256, 0, stream>>>(x, xb, x8);
    prep_w<<<dim3(32, 6), 256, 0, stream>>>(w_self0, w_neigh0, w_self1, w_neigh1,
                                            w_self2, w_neigh2, wt);
    pass_a<<<NB, 256, 0, stream>>>(src, dst, bcur, pairs);
    bucket_scan<<<1, 256, 0, stream>>>(bcur, bbase, row_start);
    pass_b<<<NB, 256, 0, stream>>>(pairs, bcur, bbase, row_start, inv_deg, srcs16);

    const int GB = (NN + 63) / 64;   // 782

    // layer 0: (xb, x8) -> (hb1, f8a)
    sage_layer<<<GB, 256, 0, stream>>>(xb, x8, row_start, srcs16, inv_deg,
                                       wt + 0 * 32768, wt + 1 * 32768, b0, hb1, f8a, nullptr);
    // layer 1: (hb1, f8a) -> (xb, f8b)
    sage_layer<<<GB, 256, 0, stream>>>(hb1, f8a, row_start, srcs16, inv_deg,
                                       wt + 2 * 32768, wt + 3 * 32768, b1, xb, f8b, nullptr);
    // layer 2: (xb, f8b) -> (hb1, f8a[dummy]), fused colsum
    sage_layer<<<GB, 256, 0, stream>>>(xb, f8b, row_start, srcs16, inv_deg,
                                       wt + 4 * 32768, wt + 5 * 32768, b2, hb1, f8a, colsum);

    head_kernel<<<1, 128, 0, stream>>>(colsum, w_head, b_head, out);
}

// Round 6
// 208.558 us; speedup vs baseline: 1.5754x; 1.5754x over previous
//
#include <hip/hip_runtime.h>
#include <hip/hip_bf16.h>
#include <hip/hip_fp8.h>
#include <stdint.h>

#define NN 50000
#define NE 800000
#define F 128
#define NCLS 16
#define NB 196          // ceil(50000/256) buckets
#define BCAP 5120       // per-bucket capacity: mean 4096 + 16 sigma
#define PA_EPT 16       // edges per thread in pass_a

typedef __attribute__((ext_vector_type(8))) short short8;
typedef __attribute__((ext_vector_type(4))) float f32x4;
typedef __attribute__((ext_vector_type(2))) float f32x2;
typedef __attribute__((ext_vector_type(4))) unsigned int uint4v;

// ---- ws byte offsets (ws_size ~256 MiB, plenty) ----
#define OB_COLSUM    0u          // float[128]
#define OB_BCUR      512u        // int[196]
#define OB_BBASE     1536u       // int[196]
#define OB_ROWSTART  4096u       // int[50001]
#define OB_INVDEG    204800u     // float[50000]
#define OB_PAIRS     409600u     // u32[196*5120]
#define OB_SRCS16    4423680u    // u16[800000]
#define OB_WT        6023680u    // bf16 6*16384 (layout L)
#define OB_XB        6220800u    // bf16 [NN][128] layout L (doubles as HB2)
#define OB_HB1       19020800u   // bf16 [NN][128] layout L
#define OB_X8        31820800u   // fp8 [NN][128] row-major (doubles as F8B)
#define OB_F8A       38220800u   // fp8 [NN][128] row-major
#define OB_NB        44620800u   // bf16 [NN][128] layout L   ends 57420800

// ---- swizzled bf16 feature layout L ----
// element (row,k) at byte: row*256 + 16*(chunk(k) ^ (row&15)) + inchunk(k)
// chunk(k) = (k>>5)*4 | ((k>>2)&3); inchunk = ((k>>4)&1)*8 + (k&3)*2
__device__ __forceinline__ uint32_t swz_off(uint32_t row, uint32_t k) {
    uint32_t c = ((k >> 5) << 2) | ((k >> 2) & 3u);
    uint32_t b = (((k >> 4) & 1u) << 3) | ((k & 3u) << 1);
    return (row << 8) + (((c ^ (row & 15u)) << 4) | b);
}

__device__ __forceinline__ uint32_t pack_bf2(float a, float b) {
    __hip_bfloat16 l = __float2bfloat16(a), h = __float2bfloat16(b);
    return ((uint32_t)(*(uint16_t*)&h) << 16) | (uint32_t)(*(uint16_t*)&l);
}

__device__ __forceinline__ uint8_t f32_to_fp8(float v) {
#if __has_builtin(__builtin_amdgcn_cvt_pk_fp8_f32)
    return (uint8_t)(__builtin_amdgcn_cvt_pk_fp8_f32(v, 0.f, 0, false) & 0xff);
#else
    __hip_fp8_e4m3 t(v);
    return t.__x;
#endif
}

__device__ __forceinline__ uint32_t f32x4_to_fp8x4(float a, float b, float c, float d) {
#if __has_builtin(__builtin_amdgcn_cvt_pk_fp8_f32)
    int r = __builtin_amdgcn_cvt_pk_fp8_f32(a, b, 0, false);
    r = __builtin_amdgcn_cvt_pk_fp8_f32(c, d, r, true);
    return (uint32_t)r;
#else
    __hip_fp8_e4m3 ta(a), tb(b), tc(c), td(d);
    return (uint32_t)ta.__x | ((uint32_t)tb.__x << 8) | ((uint32_t)tc.__x << 16) | ((uint32_t)td.__x << 24);
#endif
}

__device__ __forceinline__ void fp8x4_to_f32(uint32_t d, float& f0, float& f1, float& f2, float& f3) {
#if __has_builtin(__builtin_amdgcn_cvt_pk_f32_fp8)
    f32x2 lo = __builtin_amdgcn_cvt_pk_f32_fp8((int)d, false);
    f32x2 hi = __builtin_amdgcn_cvt_pk_f32_fp8((int)d, true);
    f0 = lo.x; f1 = lo.y; f2 = hi.x; f3 = hi.y;
#else
    __hip_fp8_e4m3 t0, t1, t2, t3;
    t0.__x = (uint8_t)(d & 0xff); t1.__x = (uint8_t)((d >> 8) & 0xff);
    t2.__x = (uint8_t)((d >> 16) & 0xff); t3.__x = (uint8_t)((d >> 24) & 0xff);
    f0 = (float)t0; f1 = (float)t1; f2 = (float)t2; f3 = (float)t3;
#endif
}

// ====== init: zero colsum, set bucket cursors to bucket bases ======
__global__ void init_kernel(float* __restrict__ colsum, int* __restrict__ bcur) {
    int t = threadIdx.x;
    if (t < 128) colsum[t] = 0.f;
    if (t < NB) bcur[t] = t * BCAP;
}

// ====== convert x to bf16 layout L + fp8 row-major copy ======
__global__ __launch_bounds__(256) void convert_x2(const float* __restrict__ x,
                                                  uint8_t* __restrict__ xb,
                                                  uint8_t* __restrict__ x8) {
    int t = blockIdx.x * 256 + threadIdx.x;          // NN*32 quad-slots
    uint32_t row = (uint32_t)t >> 5;
    uint32_t q = (uint32_t)t & 31u;                  // 4-k group
    float4 v = *(const float4*)(x + row * F + q * 4);
    uint32_t c = ((q >> 3) << 2) | (q & 3u);
    uint32_t hi = (q >> 2) & 1u;
    uint2 pk;
    pk.x = pack_bf2(v.x, v.y);
    pk.y = pack_bf2(v.z, v.w);
    *(uint2*)(xb + (row << 8) + (((c ^ (row & 15u)) << 4) | (hi << 3))) = pk;
    *(uint32_t*)(x8 + row * 128u + q * 4u) = f32x4_to_fp8x4(v.x, v.y, v.z, v.w);
}

// transpose + convert weights: Wt[n][k] = W[k][n], layout L on (n,k)
__global__ __launch_bounds__(256) void prep_w(const float* __restrict__ w0, const float* __restrict__ w1,
                                              const float* __restrict__ w2, const float* __restrict__ w3,
                                              const float* __restrict__ w4, const float* __restrict__ w5,
                                              uint8_t* __restrict__ wt) {
    int m = blockIdx.y;
    const float* w = m == 0 ? w0 : m == 1 ? w1 : m == 2 ? w2 : m == 3 ? w3 : m == 4 ? w4 : w5;
    int t = blockIdx.x * 256 + threadIdx.x;          // 8192 pair-slots
    int n = t >> 6;
    int k0 = (t & 63) << 1;
    uint32_t pk = pack_bf2(w[k0 * F + n], w[(k0 + 1) * F + n]);
    *(uint32_t*)(wt + (uint32_t)m * 32768u + swz_off((uint32_t)n, (uint32_t)k0)) = pk;
}

// ====== pass A: LDS-aggregated scatter into fixed-capacity bucket streams ======
__global__ __launch_bounds__(256) void pass_a(const int* __restrict__ src,
                                              const int* __restrict__ dst,
                                              int* __restrict__ bcur,
                                              uint32_t* __restrict__ pairs) {
    __shared__ int cnt[NB];
    __shared__ int base_s[NB];
    int t = threadIdx.x;
    for (int i = t; i < NB; i += 256) cnt[i] = 0;
    __syncthreads();

    uint32_t pk[PA_EPT];
    int bk[PA_EPT];
    int e0 = blockIdx.x * (256 * PA_EPT) + t;
#pragma unroll
    for (int j = 0; j < PA_EPT; ++j) {
        int e = e0 + j * 256;
        if (e < NE) {
            int sv = src[e], dv = dst[e];
            bk[j] = dv >> 8;
            pk[j] = (uint32_t)sv | (((uint32_t)dv & 255u) << 16);
            atomicAdd(&cnt[bk[j]], 1);
        } else bk[j] = -1;
    }
    __syncthreads();
    for (int i = t; i < NB; i += 256) {
        if (cnt[i] > 0) base_s[i] = atomicAdd(&bcur[i], cnt[i]);
        cnt[i] = 0;   // reuse as local cursor
    }
    __syncthreads();
#pragma unroll
    for (int j = 0; j < PA_EPT; ++j) {
        if (bk[j] >= 0) {
            int pos = base_s[bk[j]] + atomicAdd(&cnt[bk[j]], 1);
            pairs[pos] = pk[j];
        }
    }
}

// ====== bucket base scan (196 fills -> contiguous CSR bases) ======
__global__ __launch_bounds__(256) void bucket_scan(const int* __restrict__ bcur,
                                                   int* __restrict__ bbase,
                                                   int* __restrict__ row_start) {
    __shared__ int s[256];
    int t = threadIdx.x;
    int fill = (t < NB) ? (bcur[t] - t * BCAP) : 0;
    s[t] = fill;
    __syncthreads();
    for (int off = 1; off < 256; off <<= 1) {
        int u = (t >= off) ? s[t - off] : 0;
        __syncthreads();
        s[t] += u;
        __syncthreads();
    }
    if (t < NB) bbase[t] = s[t] - fill;   // exclusive
    if (t == 0) row_start[NN] = NE;
}

// ====== pass B: per-bucket count/scan, emit row_start+inv_deg+srcs16 ======
__global__ __launch_bounds__(256) void pass_b(const uint32_t* __restrict__ pairs,
                                              const int* __restrict__ bcur,
                                              const int* __restrict__ bbase,
                                              int* __restrict__ row_start,
                                              float* __restrict__ inv_deg,
                                              unsigned short* __restrict__ srcs) {
    __shared__ int cnt[256];
    __shared__ int s[256];
    __shared__ int cur[256];
    int b = blockIdx.x, t = threadIdx.x;
    int in0 = b * BCAP;
    int fill = bcur[b] - in0;
    int out0 = bbase[b];
    cnt[t] = 0;
    __syncthreads();
    for (int i = t; i < fill; i += 256)
        atomicAdd(&cnt[pairs[in0 + i] >> 16], 1);
    __syncthreads();
    int v = cnt[t];
    s[t] = v;
    __syncthreads();
    for (int off = 1; off < 256; off <<= 1) {
        int u = (t >= off) ? s[t - off] : 0;
        __syncthreads();
        s[t] += u;
        __syncthreads();
    }
    int excl = s[t] - v;
    cur[t] = out0 + excl;
    int row = (b << 8) + t;
    if (row < NN) {
        row_start[row] = out0 + excl;
        inv_deg[row] = 1.0f / (float)(v > 1 ? v : 1);
    }
    __syncthreads();
    for (int i = t; i < fill; i += 256) {
        uint32_t p = pairs[in0 + i];
        int pos = atomicAdd(&cur[p >> 16], 1);
        srcs[pos] = (unsigned short)(p & 0xffffu);
    }
}

// ====== aggregate: one wave per node, fp8 gather (128B rows), bf16-L output ======
__global__ __launch_bounds__(256) void aggregate_f8(
        const uint8_t* __restrict__ hf8, const int* __restrict__ row_start,
        const unsigned short* __restrict__ srcs, const float* __restrict__ inv_deg,
        uint8_t* __restrict__ nb) {
    int node = blockIdx.x * 4 + (threadIdx.x >> 6);
    int l = threadIdx.x & 63;
    int half = l >> 5;                       // two edges processed in parallel
    uint32_t sub = (uint32_t)(l & 31);       // feature dword: k = sub*4..sub*4+3
    const uint8_t* base = hf8 + sub * 4u;
    int e0 = row_start[node], e1 = row_start[node + 1];
    float a0 = 0.f, a1 = 0.f, a2 = 0.f, a3 = 0.f;

    int e = e0 + half;
    for (; e + 6 < e1; e += 8) {
        uint32_t s0 = srcs[e], s1 = srcs[e + 2], s2 = srcs[e + 4], s3 = srcs[e + 6];
        uint32_t d0 = *(const uint32_t*)(base + ((uint32_t)s0 << 7));
        uint32_t d1 = *(const uint32_t*)(base + ((uint32_t)s1 << 7));
        uint32_t d2 = *(const uint32_t*)(base + ((uint32_t)s2 << 7));
        uint32_t d3 = *(const uint32_t*)(base + ((uint32_t)s3 << 7));
        float f0, f1, f2, f3;
        fp8x4_to_f32(d0, f0, f1, f2, f3); a0 += f0; a1 += f1; a2 += f2; a3 += f3;
        fp8x4_to_f32(d1, f0, f1, f2, f3); a0 += f0; a1 += f1; a2 += f2; a3 += f3;
        fp8x4_to_f32(d2, f0, f1, f2, f3); a0 += f0; a1 += f1; a2 += f2; a3 += f3;
        fp8x4_to_f32(d3, f0, f1, f2, f3); a0 += f0; a1 += f1; a2 += f2; a3 += f3;
    }
    for (; e < e1; e += 2) {
        uint32_t s0 = srcs[e];
        uint32_t d0 = *(const uint32_t*)(base + ((uint32_t)s0 << 7));
        float f0, f1, f2, f3;
        fp8x4_to_f32(d0, f0, f1, f2, f3); a0 += f0; a1 += f1; a2 += f2; a3 += f3;
    }
    a0 += __shfl_xor(a0, 32);
    a1 += __shfl_xor(a1, 32);
    a2 += __shfl_xor(a2, 32);
    a3 += __shfl_xor(a3, 32);
    if (half == 0) {
        float idg = inv_deg[node];
        uint32_t c = ((sub >> 3) << 2) | (sub & 3u);
        uint32_t hi8 = ((sub >> 2) & 1u) << 3;
        uint2 pk;
        pk.x = pack_bf2(a0 * idg, a1 * idg);
        pk.y = pack_bf2(a2 * idg, a3 * idg);
        *(uint2*)(nb + ((uint32_t)node << 8) +
                  (((c ^ ((uint32_t)node & 15u)) << 4) | hi8)) = pk;
    }
}

// ====== MFMA GEMM: hout = relu(As@Ws + An@Wn + b); f8 mirror + opt colsum ======
__global__ __launch_bounds__(256) void gemm_mfma(
        const uint8_t* __restrict__ a_self, const uint8_t* __restrict__ a_neigh,
        const uint8_t* __restrict__ wt_self, const uint8_t* __restrict__ wt_neigh,
        const float* __restrict__ bias, uint8_t* __restrict__ hout,
        uint8_t* hout_f8, float* colsum) {
    __shared__ uint4v As4[1024];   // 16 KB
    __shared__ uint4v Ws4[2048];   // 32 KB
    __shared__ float cs[128];
    int tid = threadIdx.x;
    int lane = tid & 63, wave = tid >> 6;
    int rl = lane & 15, g = lane >> 4;
    int row0 = blockIdx.x * 64;

    f32x4 acc[8];
    f32x4 z = {0.f, 0.f, 0.f, 0.f};
#pragma unroll
    for (int nt = 0; nt < 8; ++nt) acc[nt] = z;

    const char* AsB = (const char*)As4;
    const char* WsB = (const char*)Ws4;

#pragma unroll
    for (int pass = 0; pass < 2; ++pass) {
        if (pass) __syncthreads();
        const uint4v* ga = (const uint4v*)((pass ? a_neigh : a_self) + (size_t)row0 * 256);
        const uint4v* gw = (const uint4v*)(pass ? wt_neigh : wt_self);
#pragma unroll
        for (int i = 0; i < 4; ++i) As4[tid + i * 256] = ga[tid + i * 256];
#pragma unroll
        for (int i = 0; i < 8; ++i) Ws4[tid + i * 256] = gw[tid + i * 256];
        __syncthreads();
#pragma unroll
        for (int ks = 0; ks < 4; ++ks) {
            int chunk = ((ks << 2) | g) ^ rl;
            short8 a = *(const short8*)(AsB + ((wave * 16 + rl) << 8) + (chunk << 4));
#pragma unroll
            for (int nt = 0; nt < 8; ++nt) {
                short8 bb = *(const short8*)(WsB + ((nt * 16 + rl) << 8) + (chunk << 4));
                acc[nt] = __builtin_amdgcn_mfma_f32_16x16x32_bf16(a, bb, acc[nt], 0, 0, 0);
            }
        }
    }

    bool doCol = (colsum != nullptr);
    bool doF8 = (hout_f8 != nullptr);
    if (doCol) {
        if (tid < 128) cs[tid] = 0.f;
        __syncthreads();
    }
#pragma unroll
    for (int nt = 0; nt < 8; ++nt) {
        int col = nt * 16 + rl;
        float bv = bias[col];
        float rsum = 0.f;
#pragma unroll
        for (int i = 0; i < 4; ++i) {
            int row = row0 + wave * 16 + g * 4 + i;
            if (row < NN) {
                float v = fmaxf(acc[nt][i] + bv, 0.f);
                rsum += v;
                *(__hip_bfloat16*)(hout + swz_off((uint32_t)row, (uint32_t)col)) =
                    __float2bfloat16(v);
                if (doF8) hout_f8[(uint32_t)row * 128u + (uint32_t)col] = f32_to_fp8(v);
            }
        }
        if (doCol) atomicAdd(&cs[col], rsum);
    }
    if (doCol) {
        __syncthreads();
        if (tid < 128) atomicAdd(&colsum[tid], cs[tid]);
    }
}

__global__ __launch_bounds__(128) void head_kernel(const float* __restrict__ colsum,
                                                   const float* __restrict__ w_head,
                                                   const float* __restrict__ b_head,
                                                   float* __restrict__ out) {
    __shared__ float pls[F];
    int t = threadIdx.x;
    float p = colsum[t] * (1.0f / (float)NN);
    pls[t] = p;
    out[NCLS + t] = p;
    __syncthreads();
    if (t < NCLS) {
        float sc = b_head[t];
        for (int f = 0; f < F; ++f) sc += pls[f] * w_head[f * NCLS + t];
        out[t] = sc;
    }
}

extern "C" void kernel_launch(void* const* d_in, const int* in_sizes, int n_in,
                              void* d_out, int out_size, void* d_ws, size_t ws_size,
                              hipStream_t stream) {
    const float* x       = (const float*)d_in[0];
    const int*   src     = (const int*)d_in[1];
    const int*   dst     = (const int*)d_in[2];
    const float* w_self0 = (const float*)d_in[3];
    const float* w_neigh0= (const float*)d_in[4];
    const float* b0      = (const float*)d_in[5];
    const float* w_self1 = (const float*)d_in[6];
    const float* w_neigh1= (const float*)d_in[7];
    const float* b1      = (const float*)d_in[8];
    const float* w_self2 = (const float*)d_in[9];
    const float* w_neigh2= (const float*)d_in[10];
    const float* b2      = (const float*)d_in[11];
    const float* w_head  = (const float*)d_in[12];
    const float* b_head  = (const float*)d_in[13];
    float* out = (float*)d_out;

    uint8_t* ws = (uint8_t*)d_ws;
    float* colsum   = (float*)(ws + OB_COLSUM);
    int*   bcur     = (int*)(ws + OB_BCUR);
    int*   bbase    = (int*)(ws + OB_BBASE);
    int*   row_start= (int*)(ws + OB_ROWSTART);
    float* inv_deg  = (float*)(ws + OB_INVDEG);
    uint32_t* pairs = (uint32_t*)(ws + OB_PAIRS);
    unsigned short* srcs16 = (unsigned short*)(ws + OB_SRCS16);
    uint8_t* wt     = ws + OB_WT;
    uint8_t* xb     = ws + OB_XB;     // bf16 L; doubles as hb2
    uint8_t* hb1    = ws + OB_HB1;
    uint8_t* x8     = ws + OB_X8;     // fp8; doubles as f8b
    uint8_t* f8a    = ws + OB_F8A;
    uint8_t* nb     = ws + OB_NB;

    init_kernel<<<1, 256, 0, stream>>>(colsum, bcur);
    convert_x2<<<6250, 256, 0, stream>>>(x, xb, x8);
    prep_w<<<dim3(32, 6), 256, 0, stream>>>(w_self0, w_neigh0, w_self1, w_neigh1,
                                            w_self2, w_neigh2, wt);
    pass_a<<<NB, 256, 0, stream>>>(src, dst, bcur, pairs);
    bucket_scan<<<1, 256, 0, stream>>>(bcur, bbase, row_start);
    pass_b<<<NB, 256, 0, stream>>>(pairs, bcur, bbase, row_start, inv_deg, srcs16);

    const int GB = (NN + 63) / 64;   // 782

    // layer 0: (xb, x8) -> (hb1, f8a)
    aggregate_f8<<<12500, 256, 0, stream>>>(x8, row_start, srcs16, inv_deg, nb);
    gemm_mfma<<<GB, 256, 0, stream>>>(xb, nb, wt + 0 * 32768, wt + 1 * 32768, b0,
                                      hb1, f8a, nullptr);
    // layer 1: (hb1, f8a) -> (xb, x8 as f8b)
    aggregate_f8<<<12500, 256, 0, stream>>>(f8a, row_start, srcs16, inv_deg, nb);
    gemm_mfma<<<GB, 256, 0, stream>>>(hb1, nb, wt + 2 * 32768, wt + 3 * 32768, b1,
                                      xb, x8, nullptr);
    // layer 2: (xb, x8) -> hb1, fused colsum, no f8 output
    aggregate_f8<<<12500, 256, 0, stream>>>(x8, row_start, srcs16, inv_deg, nb);
    gemm_mfma<<<GB, 256, 0, stream>>>(xb, nb, wt + 4 * 32768, wt + 5 * 32768, b2,
                                      hb1, nullptr, colsum);

    head_kernel<<<1, 128, 0, stream>>>(colsum, w_head, b_head, out);
}

// Round 7
// 198.945 us; speedup vs baseline: 1.6515x; 1.0483x over previous
//
#include <hip/hip_runtime.h>
#include <hip/hip_bf16.h>
#include <hip/hip_fp8.h>
#include <stdint.h>

#define NN 50000
#define NE 800000
#define F 128
#define NCLS 16
#define NB 196          // ceil(50000/256) buckets
#define BCAP 5120       // per-bucket capacity: mean 4096 + 16 sigma
#define PA_EPT 16       // edges per thread in pass_a

typedef __attribute__((ext_vector_type(8))) short short8;
typedef __attribute__((ext_vector_type(4))) float f32x4;
typedef __attribute__((ext_vector_type(2))) float f32x2;
typedef __attribute__((ext_vector_type(4))) unsigned int uint4v;

// ---- ws byte offsets (ws_size ~256 MiB, plenty) ----
#define OB_COLSUM    0u          // float[128]
#define OB_BCUR      512u        // int[196]
#define OB_BBASE     1536u       // int[196]
#define OB_ROWSTART  4096u       // int[50001]
#define OB_INVDEG    204800u     // float[50000]
#define OB_PAIRS     409600u     // u32[196*5120]
#define OB_SRCS16    4423680u    // u16[800000]
#define OB_WT        6023680u    // bf16 6*16384 (layout L)
#define OB_XB        6220800u    // bf16 [NN][128] layout L (doubles as HB2)
#define OB_HB1       19020800u   // bf16 [NN][128] layout L
#define OB_X8        31820800u   // fp8 [NN][128] row-major (doubles as F8B)
#define OB_F8A       38220800u   // fp8 [NN][128] row-major
#define OB_NB        44620800u   // bf16 [NN][128] layout L   ends 57420800

// ---- swizzled bf16 feature layout L ----
// element (row,k) at byte: row*256 + 16*(chunk(k) ^ (row&15)) + inchunk(k)
// chunk(k) = (k>>5)*4 | ((k>>2)&3); inchunk = ((k>>4)&1)*8 + (k&3)*2
__device__ __forceinline__ uint32_t swz_off(uint32_t row, uint32_t k) {
    uint32_t c = ((k >> 5) << 2) | ((k >> 2) & 3u);
    uint32_t b = (((k >> 4) & 1u) << 3) | ((k & 3u) << 1);
    return (row << 8) + (((c ^ (row & 15u)) << 4) | b);
}

__device__ __forceinline__ uint32_t pack_bf2(float a, float b) {
    __hip_bfloat16 l = __float2bfloat16(a), h = __float2bfloat16(b);
    return ((uint32_t)(*(uint16_t*)&h) << 16) | (uint32_t)(*(uint16_t*)&l);
}

__device__ __forceinline__ uint8_t f32_to_fp8(float v) {
#if __has_builtin(__builtin_amdgcn_cvt_pk_fp8_f32)
    return (uint8_t)(__builtin_amdgcn_cvt_pk_fp8_f32(v, 0.f, 0, false) & 0xff);
#else
    __hip_fp8_e4m3 t(v);
    return t.__x;
#endif
}

__device__ __forceinline__ uint32_t f32x4_to_fp8x4(float a, float b, float c, float d) {
#if __has_builtin(__builtin_amdgcn_cvt_pk_fp8_f32)
    int r = __builtin_amdgcn_cvt_pk_fp8_f32(a, b, 0, false);
    r = __builtin_amdgcn_cvt_pk_fp8_f32(c, d, r, true);
    return (uint32_t)r;
#else
    __hip_fp8_e4m3 ta(a), tb(b), tc(c), td(d);
    return (uint32_t)ta.__x | ((uint32_t)tb.__x << 8) | ((uint32_t)tc.__x << 16) | ((uint32_t)td.__x << 24);
#endif
}

__device__ __forceinline__ void fp8x4_to_f32(uint32_t d, float& f0, float& f1, float& f2, float& f3) {
#if __has_builtin(__builtin_amdgcn_cvt_pk_f32_fp8)
    f32x2 lo = __builtin_amdgcn_cvt_pk_f32_fp8((int)d, false);
    f32x2 hi = __builtin_amdgcn_cvt_pk_f32_fp8((int)d, true);
    f0 = lo.x; f1 = lo.y; f2 = hi.x; f3 = hi.y;
#else
    __hip_fp8_e4m3 t0, t1, t2, t3;
    t0.__x = (uint8_t)(d & 0xff); t1.__x = (uint8_t)((d >> 8) & 0xff);
    t2.__x = (uint8_t)((d >> 16) & 0xff); t3.__x = (uint8_t)((d >> 24) & 0xff);
    f0 = (float)t0; f1 = (float)t1; f2 = (float)t2; f3 = (float)t3;
#endif
}

// async global->LDS, 16B per lane (dest must be wave-uniform base + lane*16)
__device__ __forceinline__ void gload16(const void* g, void* l) {
    __builtin_amdgcn_global_load_lds(
        (const __attribute__((address_space(1))) unsigned int*)g,
        (__attribute__((address_space(3))) unsigned int*)l, 16, 0, 0);
}

// ====== convert x to bf16 layout L + fp8 row-major copy (+init fold) ======
__global__ __launch_bounds__(256) void convert_x2(const float* __restrict__ x,
                                                  uint8_t* __restrict__ xb,
                                                  uint8_t* __restrict__ x8,
                                                  float* __restrict__ colsum,
                                                  int* __restrict__ bcur) {
    if (blockIdx.x == 0) {   // init fold: colsum zeros + bucket cursors
        int tt = threadIdx.x;
        if (tt < 128) colsum[tt] = 0.f;
        if (tt < NB) bcur[tt] = tt * BCAP;
    }
    int t = blockIdx.x * 256 + threadIdx.x;          // NN*32 quad-slots
    uint32_t row = (uint32_t)t >> 5;
    uint32_t q = (uint32_t)t & 31u;                  // 4-k group
    float4 v = *(const float4*)(x + row * F + q * 4);
    uint32_t c = ((q >> 3) << 2) | (q & 3u);
    uint32_t hi = (q >> 2) & 1u;
    uint2 pk;
    pk.x = pack_bf2(v.x, v.y);
    pk.y = pack_bf2(v.z, v.w);
    *(uint2*)(xb + (row << 8) + (((c ^ (row & 15u)) << 4) | (hi << 3))) = pk;
    *(uint32_t*)(x8 + row * 128u + q * 4u) = f32x4_to_fp8x4(v.x, v.y, v.z, v.w);
}

// transpose + convert weights: Wt[n][k] = W[k][n], layout L on (n,k)
__global__ __launch_bounds__(256) void prep_w(const float* __restrict__ w0, const float* __restrict__ w1,
                                              const float* __restrict__ w2, const float* __restrict__ w3,
                                              const float* __restrict__ w4, const float* __restrict__ w5,
                                              uint8_t* __restrict__ wt) {
    int m = blockIdx.y;
    const float* w = m == 0 ? w0 : m == 1 ? w1 : m == 2 ? w2 : m == 3 ? w3 : m == 4 ? w4 : w5;
    int t = blockIdx.x * 256 + threadIdx.x;          // 8192 pair-slots
    int n = t >> 6;
    int k0 = (t & 63) << 1;
    uint32_t pk = pack_bf2(w[k0 * F + n], w[(k0 + 1) * F + n]);
    *(uint32_t*)(wt + (uint32_t)m * 32768u + swz_off((uint32_t)n, (uint32_t)k0)) = pk;
}

// ====== pass A: LDS-aggregated scatter into fixed-capacity bucket streams ======
__global__ __launch_bounds__(256) void pass_a(const int* __restrict__ src,
                                              const int* __restrict__ dst,
                                              int* __restrict__ bcur,
                                              uint32_t* __restrict__ pairs) {
    __shared__ int cnt[NB];
    __shared__ int base_s[NB];
    int t = threadIdx.x;
    for (int i = t; i < NB; i += 256) cnt[i] = 0;
    __syncthreads();

    uint32_t pk[PA_EPT];
    int bk[PA_EPT];
    int e0 = blockIdx.x * (256 * PA_EPT) + t;
#pragma unroll
    for (int j = 0; j < PA_EPT; ++j) {
        int e = e0 + j * 256;
        if (e < NE) {
            int sv = src[e], dv = dst[e];
            bk[j] = dv >> 8;
            pk[j] = (uint32_t)sv | (((uint32_t)dv & 255u) << 16);
            atomicAdd(&cnt[bk[j]], 1);
        } else bk[j] = -1;
    }
    __syncthreads();
    for (int i = t; i < NB; i += 256) {
        if (cnt[i] > 0) base_s[i] = atomicAdd(&bcur[i], cnt[i]);
        cnt[i] = 0;   // reuse as local cursor
    }
    __syncthreads();
#pragma unroll
    for (int j = 0; j < PA_EPT; ++j) {
        if (bk[j] >= 0) {
            int pos = base_s[bk[j]] + atomicAdd(&cnt[bk[j]], 1);
            pairs[pos] = pk[j];
        }
    }
}

// ====== bucket base scan (196 fills -> contiguous CSR bases) ======
__global__ __launch_bounds__(256) void bucket_scan(const int* __restrict__ bcur,
                                                   int* __restrict__ bbase,
                                                   int* __restrict__ row_start) {
    __shared__ int s[256];
    int t = threadIdx.x;
    int fill = (t < NB) ? (bcur[t] - t * BCAP) : 0;
    s[t] = fill;
    __syncthreads();
    for (int off = 1; off < 256; off <<= 1) {
        int u = (t >= off) ? s[t - off] : 0;
        __syncthreads();
        s[t] += u;
        __syncthreads();
    }
    if (t < NB) bbase[t] = s[t] - fill;   // exclusive
    if (t == 0) row_start[NN] = NE;
}

// ====== pass B: per-bucket count/scan, emit row_start+inv_deg+srcs16 ======
__global__ __launch_bounds__(256) void pass_b(const uint32_t* __restrict__ pairs,
                                              const int* __restrict__ bcur,
                                              const int* __restrict__ bbase,
                                              int* __restrict__ row_start,
                                              float* __restrict__ inv_deg,
                                              unsigned short* __restrict__ srcs) {
    __shared__ int cnt[256];
    __shared__ int s[256];
    __shared__ int cur[256];
    int b = blockIdx.x, t = threadIdx.x;
    int in0 = b * BCAP;
    int fill = bcur[b] - in0;
    int out0 = bbase[b];
    cnt[t] = 0;
    __syncthreads();
    for (int i = t; i < fill; i += 256)
        atomicAdd(&cnt[pairs[in0 + i] >> 16], 1);
    __syncthreads();
    int v = cnt[t];
    s[t] = v;
    __syncthreads();
    for (int off = 1; off < 256; off <<= 1) {
        int u = (t >= off) ? s[t - off] : 0;
        __syncthreads();
        s[t] += u;
        __syncthreads();
    }
    int excl = s[t] - v;
    cur[t] = out0 + excl;
    int row = (b << 8) + t;
    if (row < NN) {
        row_start[row] = out0 + excl;
        inv_deg[row] = 1.0f / (float)(v > 1 ? v : 1);
    }
    __syncthreads();
    for (int i = t; i < fill; i += 256) {
        uint32_t p = pairs[in0 + i];
        int pos = atomicAdd(&cur[p >> 16], 1);
        srcs[pos] = (unsigned short)(p & 0xffffu);
    }
}

// ====== aggregate: wave/node, 16 lanes x dwordx2 per row -> 4 edges/instr ======
__global__ __launch_bounds__(256) void aggregate_f8(
        const uint8_t* __restrict__ hf8, const int* __restrict__ row_start,
        const unsigned short* __restrict__ srcs, const float* __restrict__ inv_deg,
        uint8_t* __restrict__ nb) {
    int node = blockIdx.x * 4 + (threadIdx.x >> 6);
    int l = threadIdx.x & 63;
    int g = l >> 4;                          // edge slot 0..3
    uint32_t m = (uint32_t)(l & 15);         // feature octet: feats [8m, 8m+8)
    const uint8_t* base = hf8 + m * 8u;
    int e0 = row_start[node], e1 = row_start[node + 1];
    float a0=0.f,a1=0.f,a2=0.f,a3=0.f,a4=0.f,a5=0.f,a6=0.f,a7=0.f;

    int e = e0 + g;
    for (; e + 4 < e1; e += 8) {             // 8 edges in flight per wave
        uint32_t sa = srcs[e];
        uint32_t sb = srcs[e + 4];
        uint2 da = *(const uint2*)(base + ((uint32_t)sa << 7));
        uint2 db = *(const uint2*)(base + ((uint32_t)sb << 7));
        float f0, f1, f2, f3;
        fp8x4_to_f32(da.x, f0,f1,f2,f3); a0+=f0; a1+=f1; a2+=f2; a3+=f3;
        fp8x4_to_f32(da.y, f0,f1,f2,f3); a4+=f0; a5+=f1; a6+=f2; a7+=f3;
        fp8x4_to_f32(db.x, f0,f1,f2,f3); a0+=f0; a1+=f1; a2+=f2; a3+=f3;
        fp8x4_to_f32(db.y, f0,f1,f2,f3); a4+=f0; a5+=f1; a6+=f2; a7+=f3;
    }
    if (e < e1) {
        uint32_t sa = srcs[e];
        uint2 da = *(const uint2*)(base + ((uint32_t)sa << 7));
        float f0, f1, f2, f3;
        fp8x4_to_f32(da.x, f0,f1,f2,f3); a0+=f0; a1+=f1; a2+=f2; a3+=f3;
        fp8x4_to_f32(da.y, f0,f1,f2,f3); a4+=f0; a5+=f1; a6+=f2; a7+=f3;
    }
    // combine the 4 edge groups (xor 16, then 32)
    a0 += __shfl_xor(a0, 16); a1 += __shfl_xor(a1, 16);
    a2 += __shfl_xor(a2, 16); a3 += __shfl_xor(a3, 16);
    a4 += __shfl_xor(a4, 16); a5 += __shfl_xor(a5, 16);
    a6 += __shfl_xor(a6, 16); a7 += __shfl_xor(a7, 16);
    a0 += __shfl_xor(a0, 32); a1 += __shfl_xor(a1, 32);
    a2 += __shfl_xor(a2, 32); a3 += __shfl_xor(a3, 32);
    a4 += __shfl_xor(a4, 32); a5 += __shfl_xor(a5, 32);
    a6 += __shfl_xor(a6, 32); a7 += __shfl_xor(a7, 32);

    if (g == 0) {
        float idg = inv_deg[node];
        uint2 w0, w1;
        w0.x = pack_bf2(a0 * idg, a1 * idg);
        w0.y = pack_bf2(a2 * idg, a3 * idg);
        w1.x = pack_bf2(a4 * idg, a5 * idg);
        w1.y = pack_bf2(a6 * idg, a7 * idg);
        // feats [8m,8m+4) -> chunk ca half h; [8m+4,8m+8) -> chunk cb half h
        uint32_t c1 = m >> 2;
        uint32_t h  = (m >> 1) & 1u;
        uint32_t ca = (c1 << 2) | ((2u * m) & 3u);
        uint32_t cb = (c1 << 2) | ((2u * m + 1u) & 3u);
        uint32_t rx = (uint32_t)node & 15u;
        char* rowp = (char*)nb + ((uint32_t)node << 8);
        *(uint2*)(rowp + (((ca ^ rx) << 4) | (h << 3))) = w0;
        *(uint2*)(rowp + (((cb ^ rx) << 4) | (h << 3))) = w1;
    }
}

// ====== MFMA GEMM: hout = relu(As@Ws + An@Wn + b); f8 mirror + opt colsum ======
__global__ __launch_bounds__(256) void gemm_mfma(
        const uint8_t* __restrict__ a_self, const uint8_t* __restrict__ a_neigh,
        const uint8_t* __restrict__ wt_self, const uint8_t* __restrict__ wt_neigh,
        const float* __restrict__ bias, uint8_t* __restrict__ hout,
        uint8_t* hout_f8, float* colsum) {
    __shared__ uint4v As4[1024];   // 16 KB
    __shared__ uint4v Ws4[2048];   // 32 KB
    __shared__ float cs[128];
    int tid = threadIdx.x;
    int lane = tid & 63, wave = tid >> 6;
    int rl = lane & 15, g = lane >> 4;
    int row0 = blockIdx.x * 64;

    f32x4 acc[8];
    f32x4 z = {0.f, 0.f, 0.f, 0.f};
#pragma unroll
    for (int nt = 0; nt < 8; ++nt) acc[nt] = z;

    const char* AsB = (const char*)As4;
    const char* WsB = (const char*)Ws4;

#pragma unroll
    for (int pass = 0; pass < 2; ++pass) {
        if (pass) __syncthreads();
        const uint4v* ga = (const uint4v*)((pass ? a_neigh : a_self) + (size_t)row0 * 256);
        const uint4v* gw = (const uint4v*)(pass ? wt_neigh : wt_self);
#pragma unroll
        for (int i = 0; i < 4; ++i) gload16(&ga[tid + i * 256], &As4[tid + i * 256]);
#pragma unroll
        for (int i = 0; i < 8; ++i) gload16(&gw[tid + i * 256], &Ws4[tid + i * 256]);
        __syncthreads();
#pragma unroll
        for (int ks = 0; ks < 4; ++ks) {
            int chunk = ((ks << 2) | g) ^ rl;
            short8 a = *(const short8*)(AsB + ((wave * 16 + rl) << 8) + (chunk << 4));
#pragma unroll
            for (int nt = 0; nt < 8; ++nt) {
                short8 bb = *(const short8*)(WsB + ((nt * 16 + rl) << 8) + (chunk << 4));
                acc[nt] = __builtin_amdgcn_mfma_f32_16x16x32_bf16(a, bb, acc[nt], 0, 0, 0);
            }
        }
    }

    bool doCol = (colsum != nullptr);
    bool doF8 = (hout_f8 != nullptr);
    if (doCol) {
        if (tid < 128) cs[tid] = 0.f;
        __syncthreads();
    }
#pragma unroll
    for (int nt = 0; nt < 8; ++nt) {
        int col = nt * 16 + rl;
        float bv = bias[col];
        float rsum = 0.f;
#pragma unroll
        for (int i = 0; i < 4; ++i) {
            int row = row0 + wave * 16 + g * 4 + i;
            if (row < NN) {
                float v = fmaxf(acc[nt][i] + bv, 0.f);
                rsum += v;
                *(__hip_bfloat16*)(hout + swz_off((uint32_t)row, (uint32_t)col)) =
                    __float2bfloat16(v);
                if (doF8) hout_f8[(uint32_t)row * 128u + (uint32_t)col] = f32_to_fp8(v);
            }
        }
        if (doCol) atomicAdd(&cs[col], rsum);
    }
    if (doCol) {
        __syncthreads();
        if (tid < 128) atomicAdd(&colsum[tid], cs[tid]);
    }
}

__global__ __launch_bounds__(128) void head_kernel(const float* __restrict__ colsum,
                                                   const float* __restrict__ w_head,
                                                   const float* __restrict__ b_head,
                                                   float* __restrict__ out) {
    __shared__ float pls[F];
    int t = threadIdx.x;
    float p = colsum[t] * (1.0f / (float)NN);
    pls[t] = p;
    out[NCLS + t] = p;
    __syncthreads();
    if (t < NCLS) {
        float sc = b_head[t];
        for (int f = 0; f < F; ++f) sc += pls[f] * w_head[f * NCLS + t];
        out[t] = sc;
    }
}

extern "C" void kernel_launch(void* const* d_in, const int* in_sizes, int n_in,
                              void* d_out, int out_size, void* d_ws, size_t ws_size,
                              hipStream_t stream) {
    const float* x       = (const float*)d_in[0];
    const int*   src     = (const int*)d_in[1];
    const int*   dst     = (const int*)d_in[2];
    const float* w_self0 = (const float*)d_in[3];
    const float* w_neigh0= (const float*)d_in[4];
    const float* b0      = (const float*)d_in[5];
    const float* w_self1 = (const float*)d_in[6];
    const float* w_neigh1= (const float*)d_in[7];
    const float* b1      = (const float*)d_in[8];
    const float* w_self2 = (const float*)d_in[9];
    const float* w_neigh2= (const float*)d_in[10];
    const float* b2      = (const float*)d_in[11];
    const float* w_head  = (const float*)d_in[12];
    const float* b_head  = (const float*)d_in[13];
    float* out = (float*)d_out;

    uint8_t* ws = (uint8_t*)d_ws;
    float* colsum   = (float*)(ws + OB_COLSUM);
    int*   bcur     = (int*)(ws + OB_BCUR);
    int*   bbase    = (int*)(ws + OB_BBASE);
    int*   row_start= (int*)(ws + OB_ROWSTART);
    float* inv_deg  = (float*)(ws + OB_INVDEG);
    uint32_t* pairs = (uint32_t*)(ws + OB_PAIRS);
    unsigned short* srcs16 = (unsigned short*)(ws + OB_SRCS16);
    uint8_t* wt     = ws + OB_WT;
    uint8_t* xb     = ws + OB_XB;     // bf16 L; doubles as hb2
    uint8_t* hb1    = ws + OB_HB1;
    uint8_t* x8     = ws + OB_X8;     // fp8; doubles as f8b
    uint8_t* f8a    = ws + OB_F8A;
    uint8_t* nb     = ws + OB_NB;

    convert_x2<<<6250, 256, 0, stream>>>(x, xb, x8, colsum, bcur);
    prep_w<<<dim3(32, 6), 256, 0, stream>>>(w_self0, w_neigh0, w_self1, w_neigh1,
                                            w_self2, w_neigh2, wt);
    pass_a<<<NB, 256, 0, stream>>>(src, dst, bcur, pairs);
    bucket_scan<<<1, 256, 0, stream>>>(bcur, bbase, row_start);
    pass_b<<<NB, 256, 0, stream>>>(pairs, bcur, bbase, row_start, inv_deg, srcs16);

    const int GB = (NN + 63) / 64;   // 782

    // layer 0: (xb, x8) -> (hb1, f8a)
    aggregate_f8<<<12500, 256, 0, stream>>>(x8, row_start, srcs16, inv_deg, nb);
    gemm_mfma<<<GB, 256, 0, stream>>>(xb, nb, wt + 0 * 32768, wt + 1 * 32768, b0,
                                      hb1, f8a, nullptr);
    // layer 1: (hb1, f8a) -> (xb, x8 as f8b)
    aggregate_f8<<<12500, 256, 0, stream>>>(f8a, row_start, srcs16, inv_deg, nb);
    gemm_mfma<<<GB, 256, 0, stream>>>(hb1, nb, wt + 2 * 32768, wt + 3 * 32768, b1,
                                      xb, x8, nullptr);
    // layer 2: (xb, x8) -> hb1, fused colsum, no f8 output
    aggregate_f8<<<12500, 256, 0, stream>>>(x8, row_start, srcs16, inv_deg, nb);
    gemm_mfma<<<GB, 256, 0, stream>>>(xb, nb, wt + 4 * 32768, wt + 5 * 32768, b2,
                                      hb1, nullptr, colsum);

    head_kernel<<<1, 128, 0, stream>>>(colsum, w_head, b_head, out);
}